// Round 10
// baseline (261.072 us; speedup 1.0000x reference)
//
#include <hip/hip_runtime.h>
#include <hip/hip_bf16.h>

#define N_NODES 100000
#define N_EDGES 1600000
#define HID 64
#define NODE_DIM 128
#define NPB 512                              // nodes per bucket (dst>>9)
#define NBUCK ((N_NODES + NPB - 1) / NPB)    // 196
#define CAP 8960                             // fixed bucket capacity (mean 8163, +8.8 sigma)
#define EPB_A 4096                           // edges per partition block
#define NTILES (N_NODES / 16)                // 6250
#define SROW 72                              // LDS staging row stride (elements; 16B-aligned, low-conflict)

typedef __attribute__((ext_vector_type(8))) short bf16x8;
typedef __attribute__((ext_vector_type(8))) float f32x8;
typedef __attribute__((ext_vector_type(4))) float f32x4;
typedef __attribute__((ext_vector_type(2))) float f32x2;
typedef __attribute__((ext_vector_type(4))) unsigned int u32x4;

__device__ __forceinline__ unsigned short f2bf(float f) {
  __hip_bfloat16 h = __float2bfloat16(f);
  return *reinterpret_cast<unsigned short*>(&h);
}
__device__ __forceinline__ float bf2f(unsigned short u) {
  __hip_bfloat16 h = *reinterpret_cast<__hip_bfloat16*>(&u);
  return __bfloat162float(h);
}
// pack 4 floats -> 4 fp8 e4m3 bytes in one u32 (byte order a,b,c,d)
__device__ __forceinline__ unsigned int pk4(float a, float b, float c, float d) {
  unsigned int u = (unsigned)__builtin_amdgcn_cvt_pk_fp8_f32(a, b, 0, false);
  return (unsigned)__builtin_amdgcn_cvt_pk_fp8_f32(c, d, (int)u, true);
}

// pack one element of W[K][64] into MFMA B-frag order, hi/lo bf16 split
__device__ __forceinline__ void pack_one(const float* __restrict__ w,
                                         unsigned short* __restrict__ whi,
                                         unsigned short* __restrict__ wlo, int i) {
  int j = i & 7, lane = (i >> 3) & 63, ct = (i >> 9) & 3, kt = i >> 11;
  int k = kt * 32 + (lane >> 4) * 8 + j;
  int c = ct * 16 + (lane & 15);
  float v = w[k * HID + c];
  unsigned short hi = f2bf(v);
  whi[i] = hi;
  wlo[i] = f2bf(v - bf2f(hi));
}
__device__ __forceinline__ void pack_one_hi(const float* __restrict__ w,
                                            unsigned short* __restrict__ whi, int i) {
  int j = i & 7, lane = (i >> 3) & 63, ct = (i >> 9) & 3, kt = i >> 11;
  int k = kt * 32 + (lane >> 4) * 8 + j;
  int c = ct * 16 + (lane & 15);
  whi[i] = f2bf(w[k * HID + c]);
}

// ---- all weight packing + bcur init + out_mean zero, one launch ----
__global__ void k_pack_all(const float* __restrict__ enc_w, const float* __restrict__ conv_lw,
                           const float* __restrict__ conv_rw, const float* __restrict__ eh_w1,
                           unsigned short* __restrict__ encwh, unsigned short* __restrict__ encwl,
                           unsigned short* __restrict__ cw, unsigned short* __restrict__ w1s,
                           unsigned short* __restrict__ w1d, int* __restrict__ bcur,
                           float* __restrict__ out_mean) {
  int i = blockIdx.x * blockDim.x + threadIdx.x;
  if (i < NODE_DIM * HID) pack_one(enc_w, encwh, encwl, i);
  if (i < HID * HID) {
    pack_one(conv_lw, cw + 0 * 4096, cw + 1 * 4096, i);
    pack_one(conv_rw, cw + 2 * 4096, cw + 3 * 4096, i);
    pack_one(conv_lw + HID * HID, cw + 4 * 4096, cw + 5 * 4096, i);
    pack_one(conv_rw + HID * HID, cw + 6 * 4096, cw + 7 * 4096, i);
    pack_one_hi(eh_w1, w1s, i);                  // W1[0:64][:]
    pack_one_hi(eh_w1 + HID * HID, w1d, i);      // W1[64:128][:]
  }
  if (i < NBUCK) bcur[i] = i * CAP;              // fixed-capacity bucket bases
  if (i == 0) *out_mean = 0.f;
}

// ---- partition edges into fixed-capacity dst-buckets; 4B entries (src | dl<<17) ----
__global__ void k_partition(const int* __restrict__ src, const int* __restrict__ dst,
                            int* __restrict__ bcur, unsigned int* __restrict__ tbuf) {
  __shared__ int hist[NBUCK];
  for (int i = threadIdx.x; i < NBUCK; i += blockDim.x) hist[i] = 0;
  __syncthreads();
  int e0 = blockIdx.x * EPB_A;
#pragma unroll
  for (int k = 0; k < EPB_A / 256; ++k) {
    int e = e0 + k * 256 + threadIdx.x;
    if (e < N_EDGES) atomicAdd(&hist[dst[e] >> 9], 1);
  }
  __syncthreads();
  for (int b = threadIdx.x; b < NBUCK; b += blockDim.x) {
    int c = hist[b];
    hist[b] = c ? atomicAdd(&bcur[b], c) : 0;
  }
  __syncthreads();
#pragma unroll
  for (int k = 0; k < EPB_A / 256; ++k) {
    int e = e0 + k * 256 + threadIdx.x;
    if (e < N_EDGES) {
      int s = src[e], d = dst[e];
      int pos = atomicAdd(&hist[d >> 9], 1);
      tbuf[pos] = (unsigned)s | ((unsigned)(d & (NPB - 1)) << 17);
    }
  }
}

// ---- per-bucket node offsets (LDS hist+scan) + CSR rank fill; off2 = (start,end) ----
__global__ void k_bucket2(const int* __restrict__ bcur, const unsigned int* __restrict__ tbuf,
                          int* __restrict__ csr, int2* __restrict__ off2) {
  __shared__ int cnt[NPB];
  __shared__ int wsum[8];
  const int b = blockIdx.x;
  const int n0 = b * NPB;
  const int nn = min(NPB, N_NODES - n0);
  const int t0 = b * CAP, t1 = bcur[b];  // [base, base+count)
  cnt[threadIdx.x] = 0;  // blockDim == NPB == 512
  __syncthreads();
  for (int t = t0 + threadIdx.x; t < t1; t += blockDim.x)
    atomicAdd(&cnt[tbuf[t] >> 17], 1);
  __syncthreads();
  int v = (threadIdx.x < nn) ? cnt[threadIdx.x] : 0;
  int lane = threadIdx.x & 63, wid = threadIdx.x >> 6;
  int s = v;
#pragma unroll
  for (int d = 1; d < 64; d <<= 1) {
    int t = __shfl_up(s, d);
    if (lane >= d) s += t;
  }
  if (lane == 63) wsum[wid] = s;
  __syncthreads();
  if (wid == 0 && lane < 8) {
    int t = wsum[lane];
#pragma unroll
    for (int d = 1; d < 8; d <<= 1) {
      int u = __shfl_up(t, d);
      if (lane >= d) t += u;
    }
    wsum[lane] = t;
  }
  __syncthreads();
  int cur0 = t0 + (s - v) + (wid > 0 ? wsum[wid - 1] : 0);
  __syncthreads();
  if (threadIdx.x < nn) {
    off2[n0 + threadIdx.x] = make_int2(cur0, cur0 + v);
    cnt[threadIdx.x] = cur0;
  }
  __syncthreads();
  for (int t = t0 + threadIdx.x; t < t1; t += blockDim.x) {
    unsigned int u = tbuf[t];
    int pos = atomicAdd(&cnt[u >> 17], 1);
    csr[pos] = (int)(u & 0x1FFFFu);
  }
}

// ---- encoder: h = relu(x @ W + b) via MFMA; LDS-transposed epilogue writes
//      bf16 h rows + fp8 frag-order twin, all coalesced ----
__global__ void k_encode_mfma(const float* __restrict__ x, const bf16x8* __restrict__ whi,
                              const bf16x8* __restrict__ wlo, const float* __restrict__ b,
                              unsigned short* __restrict__ hbf, unsigned int* __restrict__ hq) {
  __shared__ __align__(16) unsigned short stg[4][16 * SROW];
  const int lane = threadIdx.x & 63;
  const int er = lane & 15, kb = lane >> 4;
  const int wid = threadIdx.x >> 6;
  int gw = (blockIdx.x * blockDim.x + threadIdx.x) >> 6;
  int nw = (gridDim.x * blockDim.x) >> 6;
  unsigned short* my = stg[wid];
  for (int tile = gw; tile < NTILES; tile += nw) {
    int R = tile * 16;
    f32x4 acc[4] = {{0.f, 0.f, 0.f, 0.f}, {0.f, 0.f, 0.f, 0.f}, {0.f, 0.f, 0.f, 0.f}, {0.f, 0.f, 0.f, 0.f}};
#pragma unroll
    for (int kt = 0; kt < 4; ++kt) {
      f32x8 xv = *reinterpret_cast<const f32x8*>(x + (size_t)(R + er) * NODE_DIM + kt * 32 + kb * 8);
      bf16x8 ahi, alo;
#pragma unroll
      for (int j = 0; j < 8; ++j) {
        unsigned short hi = f2bf(xv[j]);
        ahi[j] = (short)hi;
        alo[j] = (short)f2bf(xv[j] - bf2f(hi));
      }
#pragma unroll
      for (int ct = 0; ct < 4; ++ct) {
        bf16x8 bh = whi[(kt * 4 + ct) * 64 + lane];
        bf16x8 bl = wlo[(kt * 4 + ct) * 64 + lane];
        acc[ct] = __builtin_amdgcn_mfma_f32_16x16x32_bf16(ahi, bh, acc[ct], 0, 0, 0);
        acc[ct] = __builtin_amdgcn_mfma_f32_16x16x32_bf16(alo, bh, acc[ct], 0, 0, 0);
        acc[ct] = __builtin_amdgcn_mfma_f32_16x16x32_bf16(ahi, bl, acc[ct], 0, 0, 0);
      }
    }
    // stage C-frag (bf16) to wave-private LDS
#pragma unroll
    for (int ct = 0; ct < 4; ++ct) {
      float bb = b[ct * 16 + er];
#pragma unroll
      for (int r = 0; r < 4; ++r)
        my[(kb * 4 + r) * SROW + ct * 16 + er] = f2bf(fmaxf(acc[ct][r] + bb, 0.f));
    }
    // read back: lane owns node er, feature chunk kb
    bf16x8 r0 = *reinterpret_cast<const bf16x8*>(my + er * SROW + kb * 16);
    bf16x8 r1 = *reinterpret_cast<const bf16x8*>(my + er * SROW + kb * 16 + 8);
    *reinterpret_cast<bf16x8*>(hbf + (size_t)(R + er) * HID + kb * 16) = r0;
    *reinterpret_cast<bf16x8*>(hbf + (size_t)(R + er) * HID + kb * 16 + 8) = r1;
    bf16x8 q0 = *reinterpret_cast<const bf16x8*>(my + er * SROW + kb * 8);
    bf16x8 q1 = *reinterpret_cast<const bf16x8*>(my + er * SROW + 32 + kb * 8);
    u32x4 qq;
    qq[0] = pk4(bf2f((unsigned short)q0[0]), bf2f((unsigned short)q0[1]),
                bf2f((unsigned short)q0[2]), bf2f((unsigned short)q0[3]));
    qq[1] = pk4(bf2f((unsigned short)q0[4]), bf2f((unsigned short)q0[5]),
                bf2f((unsigned short)q0[6]), bf2f((unsigned short)q0[7]));
    qq[2] = pk4(bf2f((unsigned short)q1[0]), bf2f((unsigned short)q1[1]),
                bf2f((unsigned short)q1[2]), bf2f((unsigned short)q1[3]));
    qq[3] = pk4(bf2f((unsigned short)q1[4]), bf2f((unsigned short)q1[5]),
                bf2f((unsigned short)q1[6]), bf2f((unsigned short)q1[7]));
    *reinterpret_cast<u32x4*>(hq + (size_t)(R + er) * 16 + kb * 4) = qq;
  }
}

// ---- fused SAGE layer: fp8 register mean-agg + MFMA update.
//      LAST=false: writes bf16 h + fp8 twin.  LAST=true: writes f32 out_h + fused
//      P-precompute (16 MFMAs) + fp8 P rows. ----
template <bool LAST>
__global__ void k_layer(const int2* __restrict__ off2, const int* __restrict__ csr,
                        const unsigned int* __restrict__ hq_in,
                        const unsigned short* __restrict__ hbf_in,
                        const bf16x8* __restrict__ lwhi, const bf16x8* __restrict__ lwlo,
                        const float* __restrict__ lb,
                        const bf16x8* __restrict__ rwhi, const bf16x8* __restrict__ rwlo,
                        unsigned short* __restrict__ hbf_out, unsigned int* __restrict__ hq_out,
                        const bf16x8* __restrict__ w1s, const bf16x8* __restrict__ w1d,
                        unsigned int* __restrict__ pfp8, float* __restrict__ out_h) {
  __shared__ __align__(16) unsigned char stgraw[4 * 16 * SROW * (LAST ? 4 : 2)];
  const int lane = threadIdx.x & 63;
  const int er = lane & 15, kb = lane >> 4;
  const int wid = threadIdx.x >> 6;
  const int gw = (blockIdx.x * blockDim.x + threadIdx.x) >> 6;
  if (gw >= NTILES) return;
  const int R = gw * 16;
  const int n = R + er;
  const int2 se = off2[n];
  const int s0 = se.x, s1 = se.y;

  // gather-mean: one 16B fp8 load per neighbor; 8 in flight
  float a[16];
#pragma unroll
  for (int j = 0; j < 16; ++j) a[j] = 0.f;
#define ACC1(mv)                                                    \
  {                                                                 \
    _Pragma("unroll") for (int w = 0; w < 4; ++w) {                 \
      f32x2 plo = __builtin_amdgcn_cvt_pk_f32_fp8(mv[w], false);    \
      f32x2 phi = __builtin_amdgcn_cvt_pk_f32_fp8(mv[w], true);     \
      a[w * 4 + 0] += plo[0];                                       \
      a[w * 4 + 1] += plo[1];                                       \
      a[w * 4 + 2] += phi[0];                                       \
      a[w * 4 + 3] += phi[1];                                       \
    }                                                               \
  }
  int it = s0;
  for (; it + 8 <= s1; it += 8) {
    u32x4 m0 = *reinterpret_cast<const u32x4*>(hq_in + (size_t)csr[it + 0] * 16 + kb * 4);
    u32x4 m1 = *reinterpret_cast<const u32x4*>(hq_in + (size_t)csr[it + 1] * 16 + kb * 4);
    u32x4 m2 = *reinterpret_cast<const u32x4*>(hq_in + (size_t)csr[it + 2] * 16 + kb * 4);
    u32x4 m3 = *reinterpret_cast<const u32x4*>(hq_in + (size_t)csr[it + 3] * 16 + kb * 4);
    u32x4 m4 = *reinterpret_cast<const u32x4*>(hq_in + (size_t)csr[it + 4] * 16 + kb * 4);
    u32x4 m5 = *reinterpret_cast<const u32x4*>(hq_in + (size_t)csr[it + 5] * 16 + kb * 4);
    u32x4 m6 = *reinterpret_cast<const u32x4*>(hq_in + (size_t)csr[it + 6] * 16 + kb * 4);
    u32x4 m7 = *reinterpret_cast<const u32x4*>(hq_in + (size_t)csr[it + 7] * 16 + kb * 4);
    ACC1(m0) ACC1(m1) ACC1(m2) ACC1(m3) ACC1(m4) ACC1(m5) ACC1(m6) ACC1(m7)
  }
  if (it + 4 <= s1) {
    u32x4 m0 = *reinterpret_cast<const u32x4*>(hq_in + (size_t)csr[it + 0] * 16 + kb * 4);
    u32x4 m1 = *reinterpret_cast<const u32x4*>(hq_in + (size_t)csr[it + 1] * 16 + kb * 4);
    u32x4 m2 = *reinterpret_cast<const u32x4*>(hq_in + (size_t)csr[it + 2] * 16 + kb * 4);
    u32x4 m3 = *reinterpret_cast<const u32x4*>(hq_in + (size_t)csr[it + 3] * 16 + kb * 4);
    ACC1(m0) ACC1(m1) ACC1(m2) ACC1(m3)
    it += 4;
  }
  for (; it < s1; ++it) {
    u32x4 m0 = *reinterpret_cast<const u32x4*>(hq_in + (size_t)csr[it] * 16 + kb * 4);
    ACC1(m0)
  }
#undef ACC1
  const float ic = (s1 > s0) ? 1.f / (float)(s1 - s0) : 0.f;

  // self A-frags (exact bf16 h) + agg hi/lo split
  bf16x8 hv[2], ahi[2], alo[2];
  hv[0] = *reinterpret_cast<const bf16x8*>(hbf_in + (size_t)n * HID + kb * 8);
  hv[1] = *reinterpret_cast<const bf16x8*>(hbf_in + (size_t)n * HID + 32 + kb * 8);
#pragma unroll
  for (int kt = 0; kt < 2; ++kt) {
#pragma unroll
    for (int j = 0; j < 8; ++j) {
      float av = a[kt * 8 + j] * ic;
      unsigned short u = f2bf(av);
      ahi[kt][j] = (short)u;
      alo[kt][j] = (short)f2bf(av - bf2f(u));
    }
  }

  f32x4 acc[4] = {{0.f, 0.f, 0.f, 0.f}, {0.f, 0.f, 0.f, 0.f}, {0.f, 0.f, 0.f, 0.f}, {0.f, 0.f, 0.f, 0.f}};
#pragma unroll
  for (int kt = 0; kt < 2; ++kt) {
#pragma unroll
    for (int ct = 0; ct < 4; ++ct) {
      bf16x8 lh = lwhi[(kt * 4 + ct) * 64 + lane];
      bf16x8 ll = lwlo[(kt * 4 + ct) * 64 + lane];
      bf16x8 rh = rwhi[(kt * 4 + ct) * 64 + lane];
      bf16x8 rl = rwlo[(kt * 4 + ct) * 64 + lane];
      acc[ct] = __builtin_amdgcn_mfma_f32_16x16x32_bf16(ahi[kt], lh, acc[ct], 0, 0, 0);
      acc[ct] = __builtin_amdgcn_mfma_f32_16x16x32_bf16(alo[kt], lh, acc[ct], 0, 0, 0);
      acc[ct] = __builtin_amdgcn_mfma_f32_16x16x32_bf16(ahi[kt], ll, acc[ct], 0, 0, 0);
      acc[ct] = __builtin_amdgcn_mfma_f32_16x16x32_bf16(hv[kt], rh, acc[ct], 0, 0, 0);
      acc[ct] = __builtin_amdgcn_mfma_f32_16x16x32_bf16(hv[kt], rl, acc[ct], 0, 0, 0);
    }
  }

  if (!LAST) {
    unsigned short* my = reinterpret_cast<unsigned short*>(stgraw) + wid * 16 * SROW;
#pragma unroll
    for (int ct = 0; ct < 4; ++ct) {
      float bb = lb[ct * 16 + er];
#pragma unroll
      for (int r = 0; r < 4; ++r)
        my[(kb * 4 + r) * SROW + ct * 16 + er] = f2bf(fmaxf(acc[ct][r] + bb, 0.f));
    }
    bf16x8 r0 = *reinterpret_cast<const bf16x8*>(my + er * SROW + kb * 16);
    bf16x8 r1 = *reinterpret_cast<const bf16x8*>(my + er * SROW + kb * 16 + 8);
    *reinterpret_cast<bf16x8*>(hbf_out + (size_t)(R + er) * HID + kb * 16) = r0;
    *reinterpret_cast<bf16x8*>(hbf_out + (size_t)(R + er) * HID + kb * 16 + 8) = r1;
    bf16x8 q0 = *reinterpret_cast<const bf16x8*>(my + er * SROW + kb * 8);
    bf16x8 q1 = *reinterpret_cast<const bf16x8*>(my + er * SROW + 32 + kb * 8);
    u32x4 qq;
    qq[0] = pk4(bf2f((unsigned short)q0[0]), bf2f((unsigned short)q0[1]),
                bf2f((unsigned short)q0[2]), bf2f((unsigned short)q0[3]));
    qq[1] = pk4(bf2f((unsigned short)q0[4]), bf2f((unsigned short)q0[5]),
                bf2f((unsigned short)q0[6]), bf2f((unsigned short)q0[7]));
    qq[2] = pk4(bf2f((unsigned short)q1[0]), bf2f((unsigned short)q1[1]),
                bf2f((unsigned short)q1[2]), bf2f((unsigned short)q1[3]));
    qq[3] = pk4(bf2f((unsigned short)q1[4]), bf2f((unsigned short)q1[5]),
                bf2f((unsigned short)q1[6]), bf2f((unsigned short)q1[7]));
    *reinterpret_cast<u32x4*>(hq_out + (size_t)(R + er) * 16 + kb * 4) = qq;
  } else {
    float* my = reinterpret_cast<float*>(stgraw) + wid * 16 * SROW;
#pragma unroll
    for (int ct = 0; ct < 4; ++ct) {
      float bb = lb[ct * 16 + er];
#pragma unroll
      for (int r = 0; r < 4; ++r)
        my[(kb * 4 + r) * SROW + ct * 16 + er] = fmaxf(acc[ct][r] + bb, 0.f);
    }
    // f32 h rows (graded output), coalesced
#pragma unroll
    for (int c = 0; c < 4; ++c) {
      f32x4 v = *reinterpret_cast<const f32x4*>(my + er * SROW + kb * 16 + c * 4);
      *reinterpret_cast<f32x4*>(out_h + (size_t)(R + er) * HID + kb * 16 + c * 4) = v;
    }
    // fused P precompute: rebuild A-frags of h from LDS, 16 MFMAs, fp8 P rows
    f32x4 p0 = *reinterpret_cast<const f32x4*>(my + er * SROW + kb * 8);
    f32x4 p1 = *reinterpret_cast<const f32x4*>(my + er * SROW + kb * 8 + 4);
    f32x4 p2 = *reinterpret_cast<const f32x4*>(my + er * SROW + 32 + kb * 8);
    f32x4 p3 = *reinterpret_cast<const f32x4*>(my + er * SROW + 32 + kb * 8 + 4);
    bf16x8 a0, a1;
#pragma unroll
    for (int j = 0; j < 4; ++j) {
      a0[j] = (short)f2bf(p0[j]);
      a0[4 + j] = (short)f2bf(p1[j]);
      a1[j] = (short)f2bf(p2[j]);
      a1[4 + j] = (short)f2bf(p3[j]);
    }
    f32x4 as[4] = {{0.f, 0.f, 0.f, 0.f}, {0.f, 0.f, 0.f, 0.f}, {0.f, 0.f, 0.f, 0.f}, {0.f, 0.f, 0.f, 0.f}};
    f32x4 ad[4] = {{0.f, 0.f, 0.f, 0.f}, {0.f, 0.f, 0.f, 0.f}, {0.f, 0.f, 0.f, 0.f}, {0.f, 0.f, 0.f, 0.f}};
#pragma unroll
    for (int ct = 0; ct < 4; ++ct) {
      as[ct] = __builtin_amdgcn_mfma_f32_16x16x32_bf16(a0, w1s[(0 * 4 + ct) * 64 + lane], as[ct], 0, 0, 0);
      as[ct] = __builtin_amdgcn_mfma_f32_16x16x32_bf16(a1, w1s[(1 * 4 + ct) * 64 + lane], as[ct], 0, 0, 0);
      ad[ct] = __builtin_amdgcn_mfma_f32_16x16x32_bf16(a0, w1d[(0 * 4 + ct) * 64 + lane], ad[ct], 0, 0, 0);
      ad[ct] = __builtin_amdgcn_mfma_f32_16x16x32_bf16(a1, w1d[(1 * 4 + ct) * 64 + lane], ad[ct], 0, 0, 0);
    }
#pragma unroll
    for (int r = 0; r < 4; ++r) {
      int node = R + kb * 4 + r;
      pfp8[(size_t)node * 32 + er] = pk4(as[0][r], as[1][r], as[2][r], as[3][r]);
      pfp8[(size_t)node * 32 + 16 + er] = pk4(ad[0][r], ad[1][r], ad[2][r], ad[3][r]);
    }
  }
}

// ---- edge head: fp8 P gather, 4 tiles per iteration, fused mean ----
__global__ void k_edge_head_p(const int* __restrict__ src, const int* __restrict__ dst,
                              const unsigned int* __restrict__ pfp8,
                              const float* __restrict__ b1, const float* __restrict__ w2,
                              const float* __restrict__ b2, float* __restrict__ scores,
                              float* __restrict__ out_mean) {
  const int lane = threadIdx.x & 63;
  const int wid = threadIdx.x >> 6;
  const int wpb = blockDim.x >> 6;
  const int nw = gridDim.x * wpb;
  const int er = lane & 15, kb = lane >> 4;
  const int ntiles = N_EDGES / 16;  // 100000, divisible by 4
  float b1v[4][4], w2v[4][4];
#pragma unroll
  for (int q = 0; q < 4; ++q)
#pragma unroll
    for (int ct = 0; ct < 4; ++ct) {
      b1v[q][ct] = b1[ct * 16 + kb * 4 + q];
      w2v[q][ct] = w2[ct * 16 + kb * 4 + q];
    }
  const float bb = b2[0];
  float msum = 0.f;
  for (int t4 = (blockIdx.x * wpb + wid) * 4; t4 < ntiles; t4 += nw * 4) {
    u32x4 ap[4], bp[4];
#pragma unroll
    for (int k = 0; k < 4; ++k) {
      int e = (t4 + k) * 16 + er;
      int s = src[e], d = dst[e];
      ap[k] = *reinterpret_cast<const u32x4*>(pfp8 + (size_t)s * 32 + kb * 4);
      bp[k] = *reinterpret_cast<const u32x4*>(pfp8 + (size_t)d * 32 + 16 + kb * 4);
    }
    float pp[4] = {0.f, 0.f, 0.f, 0.f};
#pragma unroll
    for (int k = 0; k < 4; ++k) {
#pragma unroll
      for (int q = 0; q < 4; ++q) {
        f32x2 s01 = __builtin_amdgcn_cvt_pk_f32_fp8(ap[k][q], false);
        f32x2 s23 = __builtin_amdgcn_cvt_pk_f32_fp8(ap[k][q], true);
        f32x2 d01 = __builtin_amdgcn_cvt_pk_f32_fp8(bp[k][q], false);
        f32x2 d23 = __builtin_amdgcn_cvt_pk_f32_fp8(bp[k][q], true);
        pp[k] += fmaxf(s01[0] + d01[0] + b1v[q][0], 0.f) * w2v[q][0];
        pp[k] += fmaxf(s01[1] + d01[1] + b1v[q][1], 0.f) * w2v[q][1];
        pp[k] += fmaxf(s23[0] + d23[0] + b1v[q][2], 0.f) * w2v[q][2];
        pp[k] += fmaxf(s23[1] + d23[1] + b1v[q][3], 0.f) * w2v[q][3];
      }
    }
#pragma unroll
    for (int k = 0; k < 4; ++k) {
      pp[k] += __shfl_xor(pp[k], 16);
      pp[k] += __shfl_xor(pp[k], 32);
    }
    if (lane < 16) {
#pragma unroll
      for (int k = 0; k < 4; ++k) {
        float sc = 1.f / (1.f + __expf(-(pp[k] + bb)));
        scores[(t4 + k) * 16 + er] = sc;
        msum += sc;
      }
    }
  }
#pragma unroll
  for (int o = 1; o < 64; o <<= 1) msum += __shfl_xor(msum, o);
  __shared__ float bs[8];
  if (lane == 0) bs[wid] = msum;
  __syncthreads();
  if (threadIdx.x == 0) {
    float t = 0.f;
    for (int i = 0; i < wpb; ++i) t += bs[i];
    atomicAdd(out_mean, t * (1.f / (float)N_EDGES));
  }
}

extern "C" void kernel_launch(void* const* d_in, const int* in_sizes, int n_in,
                              void* d_out, int out_size, void* d_ws, size_t ws_size,
                              hipStream_t stream) {
  const float* x = (const float*)d_in[0];
  const int* ei = (const int*)d_in[1];
  const int* src = ei;
  const int* dst = ei + N_EDGES;
  const float* enc_w = (const float*)d_in[3];
  const float* enc_b = (const float*)d_in[4];
  const float* conv_lw = (const float*)d_in[7];
  const float* conv_lb = (const float*)d_in[8];
  const float* conv_rw = (const float*)d_in[9];
  const float* eh_w1 = (const float*)d_in[10];
  const float* eh_b1 = (const float*)d_in[11];
  const float* eh_w2 = (const float*)d_in[12];
  const float* eh_b2 = (const float*)d_in[13];

  float* out_scores = (float*)d_out;
  float* out_mean = out_scores + N_EDGES;
  float* out_h = out_mean + 1;

  char* p = (char*)d_ws;
  const size_t TB = (size_t)NBUCK * CAP;                  // padded edge slots
  unsigned int* tbuf = (unsigned int*)p;                  p += TB * 4 + 65536;
  int* csr = (int*)p;                                     p += TB * 4 + 65536;
  int2* off2 = (int2*)p;                                  p += (size_t)N_NODES * 8;
  int* bcur = (int*)p;                                    p += NBUCK * 4 + 256;
  unsigned short* h0bf = (unsigned short*)p;              p += (size_t)N_NODES * HID * 2;
  unsigned short* h1bf = (unsigned short*)p;              p += (size_t)N_NODES * HID * 2;
  unsigned int* hq0 = (unsigned int*)p;                   p += (size_t)N_NODES * 64;
  unsigned int* hq1 = (unsigned int*)p;                   p += (size_t)N_NODES * 64;
  unsigned int* pfp8 = (unsigned int*)p;                  p += (size_t)N_NODES * 128;
  unsigned short* encwh = (unsigned short*)p;             p += 8192 * 2;
  unsigned short* encwl = (unsigned short*)p;             p += 8192 * 2;
  unsigned short* cw = (unsigned short*)p;                p += 8 * 4096 * 2;
  unsigned short* w1s = (unsigned short*)p;               p += 4096 * 2;
  unsigned short* w1d = (unsigned short*)p;               p += 4096 * 2;
  const bf16x8 *lwhi0 = (const bf16x8*)(cw + 0 * 4096), *lwlo0 = (const bf16x8*)(cw + 1 * 4096);
  const bf16x8 *rwhi0 = (const bf16x8*)(cw + 2 * 4096), *rwlo0 = (const bf16x8*)(cw + 3 * 4096);
  const bf16x8 *lwhi1 = (const bf16x8*)(cw + 4 * 4096), *lwlo1 = (const bf16x8*)(cw + 5 * 4096);
  const bf16x8 *rwhi1 = (const bf16x8*)(cw + 6 * 4096), *rwlo1 = (const bf16x8*)(cw + 7 * 4096);

  // 1. packs + bcur init + mean zero
  k_pack_all<<<32, 256, 0, stream>>>(enc_w, conv_lw, conv_rw, eh_w1, encwh, encwl, cw,
                                     w1s, w1d, bcur, out_mean);
  // 2-3. bucket sort into fixed-capacity regions + per-node CSR
  k_partition<<<(N_EDGES + EPB_A - 1) / EPB_A, 256, 0, stream>>>(src, dst, bcur, tbuf);
  k_bucket2<<<NBUCK, NPB, 0, stream>>>(bcur, tbuf, csr, off2);
  // 4. encoder (bf16 h + fp8 twin, fused)
  k_encode_mfma<<<1024, 256, 0, stream>>>(x, (const bf16x8*)encwh, (const bf16x8*)encwl,
                                          enc_b, h0bf, hq0);
  // 5-6. fused SAGE layers (layer2 also emits out_h f32 + fp8 P rows)
  const int LGRID = (NTILES + 3) / 4;
  k_layer<false><<<LGRID, 256, 0, stream>>>(off2, csr, hq0, h0bf, lwhi0, lwlo0, conv_lb,
                                            rwhi0, rwlo0, h1bf, hq1,
                                            (const bf16x8*)w1s, (const bf16x8*)w1d, pfp8, out_h);
  k_layer<true><<<LGRID, 256, 0, stream>>>(off2, csr, hq1, h1bf, lwhi1, lwlo1, conv_lb + HID,
                                           rwhi1, rwlo1, h0bf, hq0,
                                           (const bf16x8*)w1s, (const bf16x8*)w1d, pfp8, out_h);
  // 7. edge head + mean
  k_edge_head_p<<<2048, 256, 0, stream>>>(src, dst, pfp8, eh_b1, eh_w2, eh_b2,
                                          out_scores, out_mean);
}

// Round 11
// 240.639 us; speedup vs baseline: 1.0849x; 1.0849x over previous
//
#include <hip/hip_runtime.h>
#include <hip/hip_bf16.h>

#define N_NODES 100000
#define N_EDGES 1600000
#define HID 64
#define NODE_DIM 128
#define NPB 512                              // nodes per bucket (dst>>9)
#define NBUCK ((N_NODES + NPB - 1) / NPB)    // 196
#define CAP 8960                             // fixed bucket capacity (mean 8163, +8.8 sigma)
#define EPB_A 4096                           // edges per partition block
#define NTILES (N_NODES / 16)                // 6250
#define SROW 72                              // LDS staging row stride (elements; 16B-aligned, low-conflict)

typedef __attribute__((ext_vector_type(8))) short bf16x8;
typedef __attribute__((ext_vector_type(8))) float f32x8;
typedef __attribute__((ext_vector_type(4))) float f32x4;
typedef __attribute__((ext_vector_type(2))) float f32x2;
typedef __attribute__((ext_vector_type(4))) unsigned int u32x4;

__device__ __forceinline__ unsigned short f2bf(float f) {
  __hip_bfloat16 h = __float2bfloat16(f);
  return *reinterpret_cast<unsigned short*>(&h);
}
__device__ __forceinline__ float bf2f(unsigned short u) {
  __hip_bfloat16 h = *reinterpret_cast<__hip_bfloat16*>(&u);
  return __bfloat162float(h);
}
// pack 4 floats -> 4 fp8 e4m3 bytes in one u32 (byte order a,b,c,d)
__device__ __forceinline__ unsigned int pk4(float a, float b, float c, float d) {
  unsigned int u = (unsigned)__builtin_amdgcn_cvt_pk_fp8_f32(a, b, 0, false);
  return (unsigned)__builtin_amdgcn_cvt_pk_fp8_f32(c, d, (int)u, true);
}

// pack one element of W[K][64] into MFMA B-frag order, hi/lo bf16 split
__device__ __forceinline__ void pack_one(const float* __restrict__ w,
                                         unsigned short* __restrict__ whi,
                                         unsigned short* __restrict__ wlo, int i) {
  int j = i & 7, lane = (i >> 3) & 63, ct = (i >> 9) & 3, kt = i >> 11;
  int k = kt * 32 + (lane >> 4) * 8 + j;
  int c = ct * 16 + (lane & 15);
  float v = w[k * HID + c];
  unsigned short hi = f2bf(v);
  whi[i] = hi;
  wlo[i] = f2bf(v - bf2f(hi));
}
__device__ __forceinline__ void pack_one_hi(const float* __restrict__ w,
                                            unsigned short* __restrict__ whi, int i) {
  int j = i & 7, lane = (i >> 3) & 63, ct = (i >> 9) & 3, kt = i >> 11;
  int k = kt * 32 + (lane >> 4) * 8 + j;
  int c = ct * 16 + (lane & 15);
  whi[i] = f2bf(w[k * HID + c]);
}

// ---- all weight packing + bcur init + out_mean zero, one launch ----
__global__ void k_pack_all(const float* __restrict__ enc_w, const float* __restrict__ conv_lw,
                           const float* __restrict__ conv_rw, const float* __restrict__ eh_w1,
                           unsigned short* __restrict__ encwh, unsigned short* __restrict__ encwl,
                           unsigned short* __restrict__ cw, unsigned short* __restrict__ w1s,
                           unsigned short* __restrict__ w1d, int* __restrict__ bcur,
                           float* __restrict__ out_mean) {
  int i = blockIdx.x * blockDim.x + threadIdx.x;
  if (i < NODE_DIM * HID) pack_one(enc_w, encwh, encwl, i);
  if (i < HID * HID) {
    pack_one(conv_lw, cw + 0 * 4096, cw + 1 * 4096, i);
    pack_one(conv_rw, cw + 2 * 4096, cw + 3 * 4096, i);
    pack_one(conv_lw + HID * HID, cw + 4 * 4096, cw + 5 * 4096, i);
    pack_one(conv_rw + HID * HID, cw + 6 * 4096, cw + 7 * 4096, i);
    pack_one_hi(eh_w1, w1s, i);                  // W1[0:64][:]
    pack_one_hi(eh_w1 + HID * HID, w1d, i);      // W1[64:128][:]
  }
  if (i < NBUCK) bcur[i] = i * CAP;              // fixed-capacity bucket bases
  if (i == 0) *out_mean = 0.f;
}

// ---- partition edges into fixed-capacity dst-buckets; 4B entries (src | dl<<17) ----
__global__ void k_partition(const int* __restrict__ src, const int* __restrict__ dst,
                            int* __restrict__ bcur, unsigned int* __restrict__ tbuf) {
  __shared__ int hist[NBUCK];
  for (int i = threadIdx.x; i < NBUCK; i += blockDim.x) hist[i] = 0;
  __syncthreads();
  int e0 = blockIdx.x * EPB_A;
#pragma unroll
  for (int k = 0; k < EPB_A / 256; ++k) {
    int e = e0 + k * 256 + threadIdx.x;
    if (e < N_EDGES) atomicAdd(&hist[dst[e] >> 9], 1);
  }
  __syncthreads();
  for (int b = threadIdx.x; b < NBUCK; b += blockDim.x) {
    int c = hist[b];
    hist[b] = c ? atomicAdd(&bcur[b], c) : 0;
  }
  __syncthreads();
#pragma unroll
  for (int k = 0; k < EPB_A / 256; ++k) {
    int e = e0 + k * 256 + threadIdx.x;
    if (e < N_EDGES) {
      int s = src[e], d = dst[e];
      int pos = atomicAdd(&hist[d >> 9], 1);
      tbuf[pos] = (unsigned)s | ((unsigned)(d & (NPB - 1)) << 17);
    }
  }
}

// ---- per-bucket node offsets (LDS hist+scan) + CSR rank fill; off2 = (start,end) ----
__global__ void k_bucket2(const int* __restrict__ bcur, const unsigned int* __restrict__ tbuf,
                          int* __restrict__ csr, int2* __restrict__ off2) {
  __shared__ int cnt[NPB];
  __shared__ int wsum[8];
  const int b = blockIdx.x;
  const int n0 = b * NPB;
  const int nn = min(NPB, N_NODES - n0);
  const int t0 = b * CAP, t1 = bcur[b];  // [base, base+count)
  cnt[threadIdx.x] = 0;  // blockDim == NPB == 512
  __syncthreads();
  for (int t = t0 + threadIdx.x; t < t1; t += blockDim.x)
    atomicAdd(&cnt[tbuf[t] >> 17], 1);
  __syncthreads();
  int v = (threadIdx.x < nn) ? cnt[threadIdx.x] : 0;
  int lane = threadIdx.x & 63, wid = threadIdx.x >> 6;
  int s = v;
#pragma unroll
  for (int d = 1; d < 64; d <<= 1) {
    int t = __shfl_up(s, d);
    if (lane >= d) s += t;
  }
  if (lane == 63) wsum[wid] = s;
  __syncthreads();
  if (wid == 0 && lane < 8) {
    int t = wsum[lane];
#pragma unroll
    for (int d = 1; d < 8; d <<= 1) {
      int u = __shfl_up(t, d);
      if (lane >= d) t += u;
    }
    wsum[lane] = t;
  }
  __syncthreads();
  int cur0 = t0 + (s - v) + (wid > 0 ? wsum[wid - 1] : 0);
  __syncthreads();
  if (threadIdx.x < nn) {
    off2[n0 + threadIdx.x] = make_int2(cur0, cur0 + v);
    cnt[threadIdx.x] = cur0;
  }
  __syncthreads();
  for (int t = t0 + threadIdx.x; t < t1; t += blockDim.x) {
    unsigned int u = tbuf[t];
    int pos = atomicAdd(&cnt[u >> 17], 1);
    csr[pos] = (int)(u & 0x1FFFFu);
  }
}

// ---- encoder: h = relu(x @ W + b) via MFMA; LDS-transposed epilogue writes
//      bf16 h rows + fp8 frag-order twin, all coalesced ----
__global__ void k_encode_mfma(const float* __restrict__ x, const bf16x8* __restrict__ whi,
                              const bf16x8* __restrict__ wlo, const float* __restrict__ b,
                              unsigned short* __restrict__ hbf, unsigned int* __restrict__ hq) {
  __shared__ __align__(16) unsigned short stg[4][16 * SROW];
  const int lane = threadIdx.x & 63;
  const int er = lane & 15, kb = lane >> 4;
  const int wid = threadIdx.x >> 6;
  int gw = (blockIdx.x * blockDim.x + threadIdx.x) >> 6;
  int nw = (gridDim.x * blockDim.x) >> 6;
  unsigned short* my = stg[wid];
  for (int tile = gw; tile < NTILES; tile += nw) {
    int R = tile * 16;
    f32x4 acc[4] = {{0.f, 0.f, 0.f, 0.f}, {0.f, 0.f, 0.f, 0.f}, {0.f, 0.f, 0.f, 0.f}, {0.f, 0.f, 0.f, 0.f}};
#pragma unroll
    for (int kt = 0; kt < 4; ++kt) {
      f32x8 xv = *reinterpret_cast<const f32x8*>(x + (size_t)(R + er) * NODE_DIM + kt * 32 + kb * 8);
      bf16x8 ahi, alo;
#pragma unroll
      for (int j = 0; j < 8; ++j) {
        unsigned short hi = f2bf(xv[j]);
        ahi[j] = (short)hi;
        alo[j] = (short)f2bf(xv[j] - bf2f(hi));
      }
#pragma unroll
      for (int ct = 0; ct < 4; ++ct) {
        bf16x8 bh = whi[(kt * 4 + ct) * 64 + lane];
        bf16x8 bl = wlo[(kt * 4 + ct) * 64 + lane];
        acc[ct] = __builtin_amdgcn_mfma_f32_16x16x32_bf16(ahi, bh, acc[ct], 0, 0, 0);
        acc[ct] = __builtin_amdgcn_mfma_f32_16x16x32_bf16(alo, bh, acc[ct], 0, 0, 0);
        acc[ct] = __builtin_amdgcn_mfma_f32_16x16x32_bf16(ahi, bl, acc[ct], 0, 0, 0);
      }
    }
    // stage C-frag (bf16) to wave-private LDS
#pragma unroll
    for (int ct = 0; ct < 4; ++ct) {
      float bb = b[ct * 16 + er];
#pragma unroll
      for (int r = 0; r < 4; ++r)
        my[(kb * 4 + r) * SROW + ct * 16 + er] = f2bf(fmaxf(acc[ct][r] + bb, 0.f));
    }
    // read back: lane owns node er, feature chunk kb
    bf16x8 r0 = *reinterpret_cast<const bf16x8*>(my + er * SROW + kb * 16);
    bf16x8 r1 = *reinterpret_cast<const bf16x8*>(my + er * SROW + kb * 16 + 8);
    *reinterpret_cast<bf16x8*>(hbf + (size_t)(R + er) * HID + kb * 16) = r0;
    *reinterpret_cast<bf16x8*>(hbf + (size_t)(R + er) * HID + kb * 16 + 8) = r1;
    bf16x8 q0 = *reinterpret_cast<const bf16x8*>(my + er * SROW + kb * 8);
    bf16x8 q1 = *reinterpret_cast<const bf16x8*>(my + er * SROW + 32 + kb * 8);
    u32x4 qq;
    qq[0] = pk4(bf2f((unsigned short)q0[0]), bf2f((unsigned short)q0[1]),
                bf2f((unsigned short)q0[2]), bf2f((unsigned short)q0[3]));
    qq[1] = pk4(bf2f((unsigned short)q0[4]), bf2f((unsigned short)q0[5]),
                bf2f((unsigned short)q0[6]), bf2f((unsigned short)q0[7]));
    qq[2] = pk4(bf2f((unsigned short)q1[0]), bf2f((unsigned short)q1[1]),
                bf2f((unsigned short)q1[2]), bf2f((unsigned short)q1[3]));
    qq[3] = pk4(bf2f((unsigned short)q1[4]), bf2f((unsigned short)q1[5]),
                bf2f((unsigned short)q1[6]), bf2f((unsigned short)q1[7]));
    *reinterpret_cast<u32x4*>(hq + (size_t)(R + er) * 16 + kb * 4) = qq;
  }
}

// ---- fused SAGE layer: fp8 register mean-agg (4-deep, R9-proven) + MFMA update.
//      LAST=false: writes bf16 h + fp8 twin.  LAST=true: writes f32 out_h + fused
//      P-precompute (16 MFMAs) + fp8 P rows. ----
template <bool LAST>
__global__ void k_layer(const int2* __restrict__ off2, const int* __restrict__ csr,
                        const unsigned int* __restrict__ hq_in,
                        const unsigned short* __restrict__ hbf_in,
                        const bf16x8* __restrict__ lwhi, const bf16x8* __restrict__ lwlo,
                        const float* __restrict__ lb,
                        const bf16x8* __restrict__ rwhi, const bf16x8* __restrict__ rwlo,
                        unsigned short* __restrict__ hbf_out, unsigned int* __restrict__ hq_out,
                        const bf16x8* __restrict__ w1s, const bf16x8* __restrict__ w1d,
                        unsigned int* __restrict__ pfp8, float* __restrict__ out_h) {
  __shared__ __align__(16) unsigned char stgraw[4 * 16 * SROW * (LAST ? 4 : 2)];
  const int lane = threadIdx.x & 63;
  const int er = lane & 15, kb = lane >> 4;
  const int wid = threadIdx.x >> 6;
  const int gw = (blockIdx.x * blockDim.x + threadIdx.x) >> 6;
  if (gw >= NTILES) return;
  const int R = gw * 16;
  const int n = R + er;
  const int2 se = off2[n];
  const int s0 = se.x, s1 = se.y;

  // gather-mean: one 16B fp8 load per neighbor, 4 in flight (R9 depth)
  float a[16];
#pragma unroll
  for (int j = 0; j < 16; ++j) a[j] = 0.f;
  int it = s0;
  for (; it + 4 <= s1; it += 4) {
    int i0 = csr[it], i1 = csr[it + 1], i2 = csr[it + 2], i3 = csr[it + 3];
    u32x4 m0 = *reinterpret_cast<const u32x4*>(hq_in + (size_t)i0 * 16 + kb * 4);
    u32x4 m1 = *reinterpret_cast<const u32x4*>(hq_in + (size_t)i1 * 16 + kb * 4);
    u32x4 m2 = *reinterpret_cast<const u32x4*>(hq_in + (size_t)i2 * 16 + kb * 4);
    u32x4 m3 = *reinterpret_cast<const u32x4*>(hq_in + (size_t)i3 * 16 + kb * 4);
#pragma unroll
    for (int w = 0; w < 4; ++w) {
      f32x2 p0 = __builtin_amdgcn_cvt_pk_f32_fp8(m0[w], false);
      f32x2 q0 = __builtin_amdgcn_cvt_pk_f32_fp8(m0[w], true);
      f32x2 p1 = __builtin_amdgcn_cvt_pk_f32_fp8(m1[w], false);
      f32x2 q1 = __builtin_amdgcn_cvt_pk_f32_fp8(m1[w], true);
      f32x2 p2 = __builtin_amdgcn_cvt_pk_f32_fp8(m2[w], false);
      f32x2 q2 = __builtin_amdgcn_cvt_pk_f32_fp8(m2[w], true);
      f32x2 p3 = __builtin_amdgcn_cvt_pk_f32_fp8(m3[w], false);
      f32x2 q3 = __builtin_amdgcn_cvt_pk_f32_fp8(m3[w], true);
      a[w * 4 + 0] += (p0[0] + p1[0]) + (p2[0] + p3[0]);
      a[w * 4 + 1] += (p0[1] + p1[1]) + (p2[1] + p3[1]);
      a[w * 4 + 2] += (q0[0] + q1[0]) + (q2[0] + q3[0]);
      a[w * 4 + 3] += (q0[1] + q1[1]) + (q2[1] + q3[1]);
    }
  }
  for (; it < s1; ++it) {
    int i0 = csr[it];
    u32x4 m0 = *reinterpret_cast<const u32x4*>(hq_in + (size_t)i0 * 16 + kb * 4);
#pragma unroll
    for (int w = 0; w < 4; ++w) {
      f32x2 p0 = __builtin_amdgcn_cvt_pk_f32_fp8(m0[w], false);
      f32x2 q0 = __builtin_amdgcn_cvt_pk_f32_fp8(m0[w], true);
      a[w * 4 + 0] += p0[0];
      a[w * 4 + 1] += p0[1];
      a[w * 4 + 2] += q0[0];
      a[w * 4 + 3] += q0[1];
    }
  }
  const float ic = (s1 > s0) ? 1.f / (float)(s1 - s0) : 0.f;

  // self A-frags (exact bf16 h) + agg hi/lo split
  bf16x8 hv[2], ahi[2], alo[2];
  hv[0] = *reinterpret_cast<const bf16x8*>(hbf_in + (size_t)n * HID + kb * 8);
  hv[1] = *reinterpret_cast<const bf16x8*>(hbf_in + (size_t)n * HID + 32 + kb * 8);
#pragma unroll
  for (int kt = 0; kt < 2; ++kt) {
#pragma unroll
    for (int j = 0; j < 8; ++j) {
      float av = a[kt * 8 + j] * ic;
      unsigned short u = f2bf(av);
      ahi[kt][j] = (short)u;
      alo[kt][j] = (short)f2bf(av - bf2f(u));
    }
  }

  f32x4 acc[4] = {{0.f, 0.f, 0.f, 0.f}, {0.f, 0.f, 0.f, 0.f}, {0.f, 0.f, 0.f, 0.f}, {0.f, 0.f, 0.f, 0.f}};
#pragma unroll
  for (int kt = 0; kt < 2; ++kt) {
#pragma unroll
    for (int ct = 0; ct < 4; ++ct) {
      bf16x8 lh = lwhi[(kt * 4 + ct) * 64 + lane];
      bf16x8 ll = lwlo[(kt * 4 + ct) * 64 + lane];
      bf16x8 rh = rwhi[(kt * 4 + ct) * 64 + lane];
      bf16x8 rl = rwlo[(kt * 4 + ct) * 64 + lane];
      acc[ct] = __builtin_amdgcn_mfma_f32_16x16x32_bf16(ahi[kt], lh, acc[ct], 0, 0, 0);
      acc[ct] = __builtin_amdgcn_mfma_f32_16x16x32_bf16(alo[kt], lh, acc[ct], 0, 0, 0);
      acc[ct] = __builtin_amdgcn_mfma_f32_16x16x32_bf16(ahi[kt], ll, acc[ct], 0, 0, 0);
      acc[ct] = __builtin_amdgcn_mfma_f32_16x16x32_bf16(hv[kt], rh, acc[ct], 0, 0, 0);
      acc[ct] = __builtin_amdgcn_mfma_f32_16x16x32_bf16(hv[kt], rl, acc[ct], 0, 0, 0);
    }
  }

  if (!LAST) {
    unsigned short* my = reinterpret_cast<unsigned short*>(stgraw) + wid * 16 * SROW;
#pragma unroll
    for (int ct = 0; ct < 4; ++ct) {
      float bb = lb[ct * 16 + er];
#pragma unroll
      for (int r = 0; r < 4; ++r)
        my[(kb * 4 + r) * SROW + ct * 16 + er] = f2bf(fmaxf(acc[ct][r] + bb, 0.f));
    }
    bf16x8 r0 = *reinterpret_cast<const bf16x8*>(my + er * SROW + kb * 16);
    bf16x8 r1 = *reinterpret_cast<const bf16x8*>(my + er * SROW + kb * 16 + 8);
    *reinterpret_cast<bf16x8*>(hbf_out + (size_t)(R + er) * HID + kb * 16) = r0;
    *reinterpret_cast<bf16x8*>(hbf_out + (size_t)(R + er) * HID + kb * 16 + 8) = r1;
    bf16x8 q0 = *reinterpret_cast<const bf16x8*>(my + er * SROW + kb * 8);
    bf16x8 q1 = *reinterpret_cast<const bf16x8*>(my + er * SROW + 32 + kb * 8);
    u32x4 qq;
    qq[0] = pk4(bf2f((unsigned short)q0[0]), bf2f((unsigned short)q0[1]),
                bf2f((unsigned short)q0[2]), bf2f((unsigned short)q0[3]));
    qq[1] = pk4(bf2f((unsigned short)q0[4]), bf2f((unsigned short)q0[5]),
                bf2f((unsigned short)q0[6]), bf2f((unsigned short)q0[7]));
    qq[2] = pk4(bf2f((unsigned short)q1[0]), bf2f((unsigned short)q1[1]),
                bf2f((unsigned short)q1[2]), bf2f((unsigned short)q1[3]));
    qq[3] = pk4(bf2f((unsigned short)q1[4]), bf2f((unsigned short)q1[5]),
                bf2f((unsigned short)q1[6]), bf2f((unsigned short)q1[7]));
    *reinterpret_cast<u32x4*>(hq_out + (size_t)(R + er) * 16 + kb * 4) = qq;
  } else {
    float* my = reinterpret_cast<float*>(stgraw) + wid * 16 * SROW;
#pragma unroll
    for (int ct = 0; ct < 4; ++ct) {
      float bb = lb[ct * 16 + er];
#pragma unroll
      for (int r = 0; r < 4; ++r)
        my[(kb * 4 + r) * SROW + ct * 16 + er] = fmaxf(acc[ct][r] + bb, 0.f);
    }
    // f32 h rows (graded output), coalesced
#pragma unroll
    for (int c = 0; c < 4; ++c) {
      f32x4 v = *reinterpret_cast<const f32x4*>(my + er * SROW + kb * 16 + c * 4);
      *reinterpret_cast<f32x4*>(out_h + (size_t)(R + er) * HID + kb * 16 + c * 4) = v;
    }
    // fused P precompute: rebuild A-frags of h from LDS, 16 MFMAs, fp8 P rows
    f32x4 p0 = *reinterpret_cast<const f32x4*>(my + er * SROW + kb * 8);
    f32x4 p1 = *reinterpret_cast<const f32x4*>(my + er * SROW + kb * 8 + 4);
    f32x4 p2 = *reinterpret_cast<const f32x4*>(my + er * SROW + 32 + kb * 8);
    f32x4 p3 = *reinterpret_cast<const f32x4*>(my + er * SROW + 32 + kb * 8 + 4);
    bf16x8 a0, a1;
#pragma unroll
    for (int j = 0; j < 4; ++j) {
      a0[j] = (short)f2bf(p0[j]);
      a0[4 + j] = (short)f2bf(p1[j]);
      a1[j] = (short)f2bf(p2[j]);
      a1[4 + j] = (short)f2bf(p3[j]);
    }
    f32x4 as[4] = {{0.f, 0.f, 0.f, 0.f}, {0.f, 0.f, 0.f, 0.f}, {0.f, 0.f, 0.f, 0.f}, {0.f, 0.f, 0.f, 0.f}};
    f32x4 ad[4] = {{0.f, 0.f, 0.f, 0.f}, {0.f, 0.f, 0.f, 0.f}, {0.f, 0.f, 0.f, 0.f}, {0.f, 0.f, 0.f, 0.f}};
#pragma unroll
    for (int ct = 0; ct < 4; ++ct) {
      as[ct] = __builtin_amdgcn_mfma_f32_16x16x32_bf16(a0, w1s[(0 * 4 + ct) * 64 + lane], as[ct], 0, 0, 0);
      as[ct] = __builtin_amdgcn_mfma_f32_16x16x32_bf16(a1, w1s[(1 * 4 + ct) * 64 + lane], as[ct], 0, 0, 0);
      ad[ct] = __builtin_amdgcn_mfma_f32_16x16x32_bf16(a0, w1d[(0 * 4 + ct) * 64 + lane], ad[ct], 0, 0, 0);
      ad[ct] = __builtin_amdgcn_mfma_f32_16x16x32_bf16(a1, w1d[(1 * 4 + ct) * 64 + lane], ad[ct], 0, 0, 0);
    }
#pragma unroll
    for (int r = 0; r < 4; ++r) {
      int node = R + kb * 4 + r;
      pfp8[(size_t)node * 32 + er] = pk4(as[0][r], as[1][r], as[2][r], as[3][r]);
      pfp8[(size_t)node * 32 + 16 + er] = pk4(ad[0][r], ad[1][r], ad[2][r], ad[3][r]);
    }
  }
}

// ---- edge head: fp8 P gather, 2 tiles per iteration (R9 depth), fused mean ----
__global__ void k_edge_head_p(const int* __restrict__ src, const int* __restrict__ dst,
                              const unsigned int* __restrict__ pfp8,
                              const float* __restrict__ b1, const float* __restrict__ w2,
                              const float* __restrict__ b2, float* __restrict__ scores,
                              float* __restrict__ out_mean) {
  const int lane = threadIdx.x & 63;
  const int wid = threadIdx.x >> 6;
  const int wpb = blockDim.x >> 6;
  const int nw = gridDim.x * wpb;
  const int er = lane & 15, kb = lane >> 4;
  const int ntiles = N_EDGES / 16;  // 100000 (even)
  float b1v[4][4], w2v[4][4];
#pragma unroll
  for (int q = 0; q < 4; ++q)
#pragma unroll
    for (int ct = 0; ct < 4; ++ct) {
      b1v[q][ct] = b1[ct * 16 + kb * 4 + q];
      w2v[q][ct] = w2[ct * 16 + kb * 4 + q];
    }
  const float bb = b2[0];
  float msum = 0.f;
  for (int t2 = (blockIdx.x * wpb + wid) * 2; t2 < ntiles; t2 += nw * 2) {
    int e0 = t2 * 16 + er;
    int e1 = e0 + 16;
    int sA = src[e0], dA = dst[e0];
    int sB = src[e1], dB = dst[e1];
    u32x4 apA = *reinterpret_cast<const u32x4*>(pfp8 + (size_t)sA * 32 + kb * 4);
    u32x4 bpA = *reinterpret_cast<const u32x4*>(pfp8 + (size_t)dA * 32 + 16 + kb * 4);
    u32x4 apB = *reinterpret_cast<const u32x4*>(pfp8 + (size_t)sB * 32 + kb * 4);
    u32x4 bpB = *reinterpret_cast<const u32x4*>(pfp8 + (size_t)dB * 32 + 16 + kb * 4);
    float pA = 0.f, pB = 0.f;
#pragma unroll
    for (int q = 0; q < 4; ++q) {
      f32x2 s01 = __builtin_amdgcn_cvt_pk_f32_fp8(apA[q], false);
      f32x2 s23 = __builtin_amdgcn_cvt_pk_f32_fp8(apA[q], true);
      f32x2 d01 = __builtin_amdgcn_cvt_pk_f32_fp8(bpA[q], false);
      f32x2 d23 = __builtin_amdgcn_cvt_pk_f32_fp8(bpA[q], true);
      pA += fmaxf(s01[0] + d01[0] + b1v[q][0], 0.f) * w2v[q][0];
      pA += fmaxf(s01[1] + d01[1] + b1v[q][1], 0.f) * w2v[q][1];
      pA += fmaxf(s23[0] + d23[0] + b1v[q][2], 0.f) * w2v[q][2];
      pA += fmaxf(s23[1] + d23[1] + b1v[q][3], 0.f) * w2v[q][3];
      f32x2 t01 = __builtin_amdgcn_cvt_pk_f32_fp8(apB[q], false);
      f32x2 t23 = __builtin_amdgcn_cvt_pk_f32_fp8(apB[q], true);
      f32x2 u01 = __builtin_amdgcn_cvt_pk_f32_fp8(bpB[q], false);
      f32x2 u23 = __builtin_amdgcn_cvt_pk_f32_fp8(bpB[q], true);
      pB += fmaxf(t01[0] + u01[0] + b1v[q][0], 0.f) * w2v[q][0];
      pB += fmaxf(t01[1] + u01[1] + b1v[q][1], 0.f) * w2v[q][1];
      pB += fmaxf(t23[0] + u23[0] + b1v[q][2], 0.f) * w2v[q][2];
      pB += fmaxf(t23[1] + u23[1] + b1v[q][3], 0.f) * w2v[q][3];
    }
    pA += __shfl_xor(pA, 16);
    pA += __shfl_xor(pA, 32);
    pB += __shfl_xor(pB, 16);
    pB += __shfl_xor(pB, 32);
    if (lane < 16) {
      float scA = 1.f / (1.f + __expf(-(pA + bb)));
      float scB = 1.f / (1.f + __expf(-(pB + bb)));
      scores[e0] = scA;
      scores[e1] = scB;
      msum += scA + scB;
    }
  }
#pragma unroll
  for (int o = 1; o < 64; o <<= 1) msum += __shfl_xor(msum, o);
  __shared__ float bs[8];
  if (lane == 0) bs[wid] = msum;
  __syncthreads();
  if (threadIdx.x == 0) {
    float t = 0.f;
    for (int i = 0; i < wpb; ++i) t += bs[i];
    atomicAdd(out_mean, t * (1.f / (float)N_EDGES));
  }
}

extern "C" void kernel_launch(void* const* d_in, const int* in_sizes, int n_in,
                              void* d_out, int out_size, void* d_ws, size_t ws_size,
                              hipStream_t stream) {
  const float* x = (const float*)d_in[0];
  const int* ei = (const int*)d_in[1];
  const int* src = ei;
  const int* dst = ei + N_EDGES;
  const float* enc_w = (const float*)d_in[3];
  const float* enc_b = (const float*)d_in[4];
  const float* conv_lw = (const float*)d_in[7];
  const float* conv_lb = (const float*)d_in[8];
  const float* conv_rw = (const float*)d_in[9];
  const float* eh_w1 = (const float*)d_in[10];
  const float* eh_b1 = (const float*)d_in[11];
  const float* eh_w2 = (const float*)d_in[12];
  const float* eh_b2 = (const float*)d_in[13];

  float* out_scores = (float*)d_out;
  float* out_mean = out_scores + N_EDGES;
  float* out_h = out_mean + 1;

  char* p = (char*)d_ws;
  const size_t TB = (size_t)NBUCK * CAP;                  // padded edge slots
  unsigned int* tbuf = (unsigned int*)p;                  p += TB * 4 + 65536;
  int* csr = (int*)p;                                     p += TB * 4 + 65536;
  int2* off2 = (int2*)p;                                  p += (size_t)N_NODES * 8;
  int* bcur = (int*)p;                                    p += NBUCK * 4 + 256;
  unsigned short* h0bf = (unsigned short*)p;              p += (size_t)N_NODES * HID * 2;
  unsigned short* h1bf = (unsigned short*)p;              p += (size_t)N_NODES * HID * 2;
  unsigned int* hq0 = (unsigned int*)p;                   p += (size_t)N_NODES * 64;
  unsigned int* hq1 = (unsigned int*)p;                   p += (size_t)N_NODES * 64;
  unsigned int* pfp8 = (unsigned int*)p;                  p += (size_t)N_NODES * 128;
  unsigned short* encwh = (unsigned short*)p;             p += 8192 * 2;
  unsigned short* encwl = (unsigned short*)p;             p += 8192 * 2;
  unsigned short* cw = (unsigned short*)p;                p += 8 * 4096 * 2;
  unsigned short* w1s = (unsigned short*)p;               p += 4096 * 2;
  unsigned short* w1d = (unsigned short*)p;               p += 4096 * 2;
  const bf16x8 *lwhi0 = (const bf16x8*)(cw + 0 * 4096), *lwlo0 = (const bf16x8*)(cw + 1 * 4096);
  const bf16x8 *rwhi0 = (const bf16x8*)(cw + 2 * 4096), *rwlo0 = (const bf16x8*)(cw + 3 * 4096);
  const bf16x8 *lwhi1 = (const bf16x8*)(cw + 4 * 4096), *lwlo1 = (const bf16x8*)(cw + 5 * 4096);
  const bf16x8 *rwhi1 = (const bf16x8*)(cw + 6 * 4096), *rwlo1 = (const bf16x8*)(cw + 7 * 4096);

  // 1. packs + bcur init + mean zero
  k_pack_all<<<32, 256, 0, stream>>>(enc_w, conv_lw, conv_rw, eh_w1, encwh, encwl, cw,
                                     w1s, w1d, bcur, out_mean);
  // 2-3. bucket sort into fixed-capacity regions + per-node CSR
  k_partition<<<(N_EDGES + EPB_A - 1) / EPB_A, 256, 0, stream>>>(src, dst, bcur, tbuf);
  k_bucket2<<<NBUCK, NPB, 0, stream>>>(bcur, tbuf, csr, off2);
  // 4. encoder (bf16 h + fp8 twin, fused)
  k_encode_mfma<<<1024, 256, 0, stream>>>(x, (const bf16x8*)encwh, (const bf16x8*)encwl,
                                          enc_b, h0bf, hq0);
  // 5-6. fused SAGE layers (layer2 also emits out_h f32 + fp8 P rows)
  const int LGRID = (NTILES + 3) / 4;
  k_layer<false><<<LGRID, 256, 0, stream>>>(off2, csr, hq0, h0bf, lwhi0, lwlo0, conv_lb,
                                            rwhi0, rwlo0, h1bf, hq1,
                                            (const bf16x8*)w1s, (const bf16x8*)w1d, pfp8, out_h);
  k_layer<true><<<LGRID, 256, 0, stream>>>(off2, csr, hq1, h1bf, lwhi1, lwlo1, conv_lb + HID,
                                           rwhi1, rwlo1, h0bf, hq0,
                                           (const bf16x8*)w1s, (const bf16x8*)w1d, pfp8, out_h);
  // 7. edge head + mean
  k_edge_head_p<<<2048, 256, 0, stream>>>(src, dst, pfp8, eh_b1, eh_w2, eh_b2,
                                          out_scores, out_mean);
}